// Round 1
// baseline (426.629 us; speedup 1.0000x reference)
//
#include <hip/hip_runtime.h>

typedef unsigned short ushort_t;
typedef __bf16 bf16x8 __attribute__((ext_vector_type(8)));
typedef float f32x4 __attribute__((ext_vector_type(4)));

__device__ __forceinline__ ushort_t f2bf(float f) {
  unsigned u = __float_as_uint(f);
  u += 0x7fff + ((u >> 16) & 1);
  return (ushort_t)(u >> 16);
}

// ---------------- weight fp32 -> bf16 ----------------
__global__ __launch_bounds__(256) void cvt_weights(
    const float* __restrict__ wq, const float* __restrict__ wk,
    const float* __restrict__ wv, const float* __restrict__ wo,
    ushort_t* __restrict__ dst) {
  int i = blockIdx.x * 256 + threadIdx.x;  // 262144 per matrix
  dst[i]          = f2bf(wq[i]);
  dst[262144 + i] = f2bf(wk[i]);
  dst[524288 + i] = f2bf(wv[i]);
  dst[786432 + i] = f2bf(wo[i]);
}

// ---------------- group norm stats: one block per (b,g) ----------------
__global__ __launch_bounds__(256) void gn_stats(const float* __restrict__ x,
                                                float* __restrict__ stats) {
  const float4* p = (const float4*)(x + (size_t)blockIdx.x * 65536);
  float s = 0.f, ss = 0.f;
  for (int i = threadIdx.x; i < 16384; i += 256) {
    float4 v = p[i];
    s += v.x + v.y + v.z + v.w;
    ss += v.x * v.x + v.y * v.y + v.z * v.z + v.w * v.w;
  }
  for (int off = 32; off; off >>= 1) {
    s += __shfl_xor(s, off, 64);
    ss += __shfl_xor(ss, off, 64);
  }
  __shared__ float sh[8];
  int wave = threadIdx.x >> 6, lane = threadIdx.x & 63;
  if (lane == 0) { sh[wave] = s; sh[4 + wave] = ss; }
  __syncthreads();
  if (threadIdx.x == 0) {
    s = sh[0] + sh[1] + sh[2] + sh[3];
    ss = sh[4] + sh[5] + sh[6] + sh[7];
    float mean = s * (1.f / 65536.f);
    float var = ss * (1.f / 65536.f) - mean * mean;
    stats[blockIdx.x * 2] = mean;
    stats[blockIdx.x * 2 + 1] = rsqrtf(var + 1e-6f);
  }
}

// ---------------- GN apply + transpose: x (b,c,n) -> hnT (b,n,c) bf16 ----------------
__global__ __launch_bounds__(256) void gn_apply(
    const float* __restrict__ x, const float* __restrict__ gamma,
    const float* __restrict__ beta, const float* __restrict__ stats,
    ushort_t* __restrict__ hnT) {
  __shared__ float T[32][33];
  int i0 = blockIdx.x * 32, c0 = blockIdx.y * 32, b = blockIdx.z;
  int tx = threadIdx.x, ty = threadIdx.y;  // (32,8)
#pragma unroll
  for (int k = 0; k < 4; k++) {
    int cl = ty + k * 8;
    int c = c0 + cl;
    int bg = (b * 32 + (c >> 4)) * 2;
    float mean = stats[bg], rstd = stats[bg + 1];
    float v = x[((size_t)(b * 512 + c)) * 4096 + i0 + tx];
    T[cl][tx] = (v - mean) * rstd * gamma[c] + beta[c];
  }
  __syncthreads();
#pragma unroll
  for (int k = 0; k < 4; k++) {
    int il = ty + k * 8;
    hnT[((size_t)b * 4096 + i0 + il) * 512 + c0 + tx] = f2bf(T[tx][il]);
  }
}

// ---------------- generic C = A * B^T GEMM (bf16 in, fp32 acc) ----------------
// A: M x K row-major (per-batch stride sA), B: N x K row-major (stride sB)
// out[m,n] = (sum_k A[m,k]B[n,k] + bias) * scale  [+resid, fp32 out]
__global__ __launch_bounds__(256) void gemm_abt(
    const ushort_t* __restrict__ A, long long sA,
    const ushort_t* __restrict__ B, long long sB,
    int K, int N,
    ushort_t* __restrict__ outB, long long sC,
    const float* __restrict__ bias, int bias_mode, float scale,
    float* __restrict__ outF, const float* __restrict__ resid) {
  __shared__ __align__(16) ushort_t As[128][40];
  __shared__ __align__(16) ushort_t Bs[128][40];
  const ushort_t* Ab = A + (size_t)blockIdx.z * sA;
  const ushort_t* Bb = B + (size_t)blockIdx.z * sB;
  int m0 = blockIdx.y * 128, n0 = blockIdx.x * 128;
  int t = threadIdx.x;
  int lane = t & 63;
  int quad = lane >> 4, l16 = lane & 15;
  int wave = t >> 6;
  int wm = (wave >> 1) * 64, wn = (wave & 1) * 64;

  f32x4 acc[4][4];
#pragma unroll
  for (int i = 0; i < 4; i++)
#pragma unroll
    for (int j = 0; j < 4; j++)
#pragma unroll
      for (int r = 0; r < 4; r++) acc[i][j][r] = 0.f;

  int r0 = t >> 2, ch = t & 3;  // slots t and t+256 -> rows r0, r0+64
  for (int k0 = 0; k0 < K; k0 += 32) {
    __syncthreads();
    *(uint4*)&As[r0][ch * 8]      = *(const uint4*)(Ab + (size_t)(m0 + r0) * K + k0 + ch * 8);
    *(uint4*)&As[r0 + 64][ch * 8] = *(const uint4*)(Ab + (size_t)(m0 + r0 + 64) * K + k0 + ch * 8);
    *(uint4*)&Bs[r0][ch * 8]      = *(const uint4*)(Bb + (size_t)(n0 + r0) * K + k0 + ch * 8);
    *(uint4*)&Bs[r0 + 64][ch * 8] = *(const uint4*)(Bb + (size_t)(n0 + r0 + 64) * K + k0 + ch * 8);
    __syncthreads();
    bf16x8 af[4], bfr[4];
#pragma unroll
    for (int i = 0; i < 4; i++) {
      af[i]  = *(const bf16x8*)&As[wm + i * 16 + l16][quad * 8];
      bfr[i] = *(const bf16x8*)&Bs[wn + i * 16 + l16][quad * 8];
    }
#pragma unroll
    for (int mi = 0; mi < 4; mi++)
#pragma unroll
      for (int ni = 0; ni < 4; ni++)
        acc[mi][ni] = __builtin_amdgcn_mfma_f32_16x16x32_bf16(af[mi], bfr[ni], acc[mi][ni], 0, 0, 0);
  }

  size_t cbase = (size_t)blockIdx.z * sC;
#pragma unroll
  for (int mi = 0; mi < 4; mi++) {
#pragma unroll
    for (int ni = 0; ni < 4; ni++) {
      int gm = m0 + wm + mi * 16 + quad * 4;
      int gn = n0 + wn + ni * 16 + l16;
#pragma unroll
      for (int r = 0; r < 4; r++) {
        float val = acc[mi][ni][r];
        int m = gm + r;
        if (bias_mode == 1) val += bias[m];
        else if (bias_mode == 2) val += bias[gn];
        val *= scale;
        size_t idx = cbase + (size_t)m * N + gn;
        if (outF) outF[idx] = val + resid[idx];
        else outB[idx] = f2bf(val);
      }
    }
  }
}

// ---------------- row softmax in place on bf16 S (4096 cols) ----------------
__global__ __launch_bounds__(256) void softmax_rows(ushort_t* __restrict__ S) {
  uint4* p = (uint4*)(S + (size_t)blockIdx.x * 4096);
  int t = threadIdx.x;
  uint4 d0 = p[t * 2], d1 = p[t * 2 + 1];
  unsigned u[8] = {d0.x, d0.y, d0.z, d0.w, d1.x, d1.y, d1.z, d1.w};
  float v[16];
#pragma unroll
  for (int i = 0; i < 8; i++) {
    v[2 * i]     = __uint_as_float(u[i] << 16);
    v[2 * i + 1] = __uint_as_float(u[i] & 0xffff0000u);
  }
  float m = v[0];
#pragma unroll
  for (int i = 1; i < 16; i++) m = fmaxf(m, v[i]);
  for (int off = 32; off; off >>= 1) m = fmaxf(m, __shfl_xor(m, off, 64));
  __shared__ float sh[8];
  int wave = t >> 6, lane = t & 63;
  if (lane == 0) sh[wave] = m;
  __syncthreads();
  m = fmaxf(fmaxf(sh[0], sh[1]), fmaxf(sh[2], sh[3]));
  float sum = 0.f;
#pragma unroll
  for (int i = 0; i < 16; i++) { v[i] = __expf(v[i] - m); sum += v[i]; }
  for (int off = 32; off; off >>= 1) sum += __shfl_xor(sum, off, 64);
  if (lane == 0) sh[4 + wave] = sum;
  __syncthreads();
  float inv = 1.f / (sh[4] + sh[5] + sh[6] + sh[7]);
  unsigned o[8];
#pragma unroll
  for (int i = 0; i < 8; i++)
    o[i] = (unsigned)f2bf(v[2 * i] * inv) | ((unsigned)f2bf(v[2 * i + 1] * inv) << 16);
  p[t * 2]     = make_uint4(o[0], o[1], o[2], o[3]);
  p[t * 2 + 1] = make_uint4(o[4], o[5], o[6], o[7]);
}

extern "C" void kernel_launch(void* const* d_in, const int* in_sizes, int n_in,
                              void* d_out, int out_size, void* d_ws, size_t ws_size,
                              hipStream_t stream) {
  const float* x     = (const float*)d_in[0];
  const float* gamma = (const float*)d_in[1];
  const float* beta  = (const float*)d_in[2];
  const float* wq    = (const float*)d_in[3];
  const float* bq    = (const float*)d_in[4];
  const float* wk    = (const float*)d_in[5];
  const float* bk    = (const float*)d_in[6];
  const float* wv    = (const float*)d_in[7];
  const float* bv    = (const float*)d_in[8];
  const float* wo    = (const float*)d_in[9];
  const float* bo    = (const float*)d_in[10];
  float* out = (float*)d_out;

  // workspace layout (bf16 elements)
  ushort_t* wb  = (ushort_t*)d_ws;
  ushort_t* wqb = wb;
  ushort_t* wkb = wb + 262144;
  ushort_t* wvb = wb + 524288;
  ushort_t* wob = wb + 786432;
  ushort_t* hnT = wb + 1048576;        // 2 x 4096 x 512
  ushort_t* qT  = hnT + 4194304;       // 2 x 4096 x 512 (i,o)
  ushort_t* kT  = qT + 4194304;
  ushort_t* vC  = kT + 4194304;        // 2 x 512 x 4096 (c,i)
  ushort_t* OT  = vC + 4194304;        // 2 x 4096 x 512 (i,c)
  ushort_t* S   = OT + 4194304;        // 2 x 4096 x 4096
  float* stats  = (float*)(S + 33554432);  // 64 x (mean,rstd)

  const long long HS = 2097152;   // 4096*512 per batch
  const long long SS = 16777216;  // 4096*4096 per batch
  const float scale = 0.044194173824159216f;  // 512^-0.5

  cvt_weights<<<dim3(1024), dim3(256), 0, stream>>>(wq, wk, wv, wo, wb);
  gn_stats<<<dim3(64), dim3(256), 0, stream>>>(x, stats);
  gn_apply<<<dim3(128, 16, 2), dim3(32, 8), 0, stream>>>(x, gamma, beta, stats, hnT);
  // qT = hnT * wq^T  (M=4096,N=512,K=512), bias over n, x scale (folded)
  gemm_abt<<<dim3(4, 32, 2), dim3(256), 0, stream>>>(hnT, HS, wqb, 0, 512, 512, qT, HS, bq, 2, scale, nullptr, nullptr);
  // kT = hnT * wk^T
  gemm_abt<<<dim3(4, 32, 2), dim3(256), 0, stream>>>(hnT, HS, wkb, 0, 512, 512, kT, HS, bk, 2, 1.f, nullptr, nullptr);
  // v = wv * hnT^T  (M=512,N=4096,K=512), bias over m
  gemm_abt<<<dim3(32, 4, 2), dim3(256), 0, stream>>>(wvb, 0, hnT, HS, 512, 4096, vC, HS, bv, 1, 1.f, nullptr, nullptr);
  // S = qT * kT^T (M=N=4096, K=512), scale already in q
  gemm_abt<<<dim3(32, 32, 2), dim3(256), 0, stream>>>(qT, HS, kT, HS, 512, 4096, S, SS, nullptr, 0, 1.f, nullptr, nullptr);
  // softmax rows (8192 rows over both batches)
  softmax_rows<<<dim3(8192), dim3(256), 0, stream>>>(S);
  // OT = P * v^T (M=4096, N=512, K=4096)
  gemm_abt<<<dim3(4, 32, 2), dim3(256), 0, stream>>>(S, SS, vC, HS, 4096, 512, OT, HS, nullptr, 0, 1.f, nullptr, nullptr);
  // y = wo * OT^T + bo + x (M=512, N=4096, K=512), fp32 out with residual
  gemm_abt<<<dim3(32, 4, 2), dim3(256), 0, stream>>>(wob, 0, OT, HS, 512, 4096, nullptr, HS, bo, 1, 1.f, out, x);
}

// Round 2
// 416.077 us; speedup vs baseline: 1.0254x; 1.0254x over previous
//
#include <hip/hip_runtime.h>

typedef unsigned short ushort_t;
typedef __bf16 bf16x8 __attribute__((ext_vector_type(8)));
typedef float f32x4 __attribute__((ext_vector_type(4)));

__device__ __forceinline__ ushort_t f2bf(float f) {
  unsigned u = __float_as_uint(f);
  u += 0x7fff + ((u >> 16) & 1);
  return (ushort_t)(u >> 16);
}

// async global -> LDS, 16B per lane (wave stages 1024B contiguous)
__device__ __forceinline__ void gload16(const void* g, void* l) {
  __builtin_amdgcn_global_load_lds(
      (const __attribute__((address_space(1))) unsigned int*)g,
      (__attribute__((address_space(3))) unsigned int*)l, 16, 0, 0);
}

// ---------------- weight fp32 -> bf16 ----------------
__global__ __launch_bounds__(256) void cvt_weights(
    const float* __restrict__ wq, const float* __restrict__ wk,
    const float* __restrict__ wv, const float* __restrict__ wo,
    ushort_t* __restrict__ dst) {
  int i = blockIdx.x * 256 + threadIdx.x;  // 262144 per matrix
  dst[i]          = f2bf(wq[i]);
  dst[262144 + i] = f2bf(wk[i]);
  dst[524288 + i] = f2bf(wv[i]);
  dst[786432 + i] = f2bf(wo[i]);
}

// ---------------- group norm stats: one block per (b,g) ----------------
__global__ __launch_bounds__(256) void gn_stats(const float* __restrict__ x,
                                                float* __restrict__ stats) {
  const float4* p = (const float4*)(x + (size_t)blockIdx.x * 65536);
  float s = 0.f, ss = 0.f;
  for (int i = threadIdx.x; i < 16384; i += 256) {
    float4 v = p[i];
    s += v.x + v.y + v.z + v.w;
    ss += v.x * v.x + v.y * v.y + v.z * v.z + v.w * v.w;
  }
  for (int off = 32; off; off >>= 1) {
    s += __shfl_xor(s, off, 64);
    ss += __shfl_xor(ss, off, 64);
  }
  __shared__ float sh[8];
  int wave = threadIdx.x >> 6, lane = threadIdx.x & 63;
  if (lane == 0) { sh[wave] = s; sh[4 + wave] = ss; }
  __syncthreads();
  if (threadIdx.x == 0) {
    s = sh[0] + sh[1] + sh[2] + sh[3];
    ss = sh[4] + sh[5] + sh[6] + sh[7];
    float mean = s * (1.f / 65536.f);
    float var = ss * (1.f / 65536.f) - mean * mean;
    stats[blockIdx.x * 2] = mean;
    stats[blockIdx.x * 2 + 1] = rsqrtf(var + 1e-6f);
  }
}

// ---------------- GN apply + transpose: x (b,c,n) -> hnT (b,n,c) bf16 ----------------
__global__ __launch_bounds__(256) void gn_apply(
    const float* __restrict__ x, const float* __restrict__ gamma,
    const float* __restrict__ beta, const float* __restrict__ stats,
    ushort_t* __restrict__ hnT) {
  __shared__ float T[32][33];
  int i0 = blockIdx.x * 32, c0 = blockIdx.y * 32, b = blockIdx.z;
  int tx = threadIdx.x, ty = threadIdx.y;  // (32,8)
#pragma unroll
  for (int k = 0; k < 4; k++) {
    int cl = ty + k * 8;
    int c = c0 + cl;
    int bg = (b * 32 + (c >> 4)) * 2;
    float mean = stats[bg], rstd = stats[bg + 1];
    float v = x[((size_t)(b * 512 + c)) * 4096 + i0 + tx];
    T[cl][tx] = (v - mean) * rstd * gamma[c] + beta[c];
  }
  __syncthreads();
#pragma unroll
  for (int k = 0; k < 4; k++) {
    int il = ty + k * 8;
    hnT[((size_t)b * 4096 + i0 + il) * 512 + c0 + tx] = f2bf(T[tx][il]);
  }
}

// ---------------- generic C = A * B^T GEMM (bf16 in, fp32 acc) ----------------
// A: M x K row-major (per-batch stride sA), B: N x K row-major (stride sB)
// out[m,n] = (sum_k A[m,k]B[n,k] + bias) * scale  [+resid, fp32 out]
// LDS staged via global_load_lds (UNPADDED tiles; wave-uniform base + lane*16).
__global__ __launch_bounds__(256) void gemm_abt(
    const ushort_t* __restrict__ A, long long sA,
    const ushort_t* __restrict__ B, long long sB,
    int K, int N,
    ushort_t* __restrict__ outB, long long sC,
    const float* __restrict__ bias, int bias_mode, float scale,
    float* __restrict__ outF, const float* __restrict__ resid) {
  __shared__ __align__(16) ushort_t As[128][32];
  __shared__ __align__(16) ushort_t Bs[128][32];
  const ushort_t* Ab = A + (size_t)blockIdx.z * sA;
  const ushort_t* Bb = B + (size_t)blockIdx.z * sB;
  int m0 = blockIdx.y * 128, n0 = blockIdx.x * 128;
  int t = threadIdx.x;
  int lane = t & 63;
  int quad = lane >> 4, l16 = lane & 15;
  int wave = t >> 6;
  int wm = (wave >> 1) * 64, wn = (wave & 1) * 64;

  f32x4 acc[4][4];
#pragma unroll
  for (int i = 0; i < 4; i++)
#pragma unroll
    for (int j = 0; j < 4; j++)
#pragma unroll
      for (int r = 0; r < 4; r++) acc[i][j][r] = 0.f;

  // staging: wave w handles chunks {2w, 2w+1}; chunk = 16 rows x 32 cols.
  // lane i -> row chunk*16 + (i>>2), k-offset (i&3)*8 elements (16B).
  int chunk = wave * 2;
  int srow = chunk * 16 + (lane >> 2);
  int skoff = (lane & 3) * 8;
  const ushort_t* gA0 = Ab + (size_t)(m0 + srow) * K + skoff;
  const ushort_t* gA1 = gA0 + (size_t)16 * K;
  const ushort_t* gB0 = Bb + (size_t)(n0 + srow) * K + skoff;
  const ushort_t* gB1 = gB0 + (size_t)16 * K;
  char* lA = (char*)&As[0][0] + chunk * 1024 + lane * 16;
  char* lB = (char*)&Bs[0][0] + chunk * 1024 + lane * 16;

  for (int k0 = 0; k0 < K; k0 += 32) {
    __syncthreads();
    gload16(gA0 + k0, lA);
    gload16(gA1 + k0, lA + 1024);
    gload16(gB0 + k0, lB);
    gload16(gB1 + k0, lB + 1024);
    __syncthreads();
    bf16x8 af[4], bfr[4];
#pragma unroll
    for (int i = 0; i < 4; i++) {
      af[i]  = *(const bf16x8*)&As[wm + i * 16 + l16][quad * 8];
      bfr[i] = *(const bf16x8*)&Bs[wn + i * 16 + l16][quad * 8];
    }
#pragma unroll
    for (int mi = 0; mi < 4; mi++)
#pragma unroll
      for (int ni = 0; ni < 4; ni++)
        acc[mi][ni] = __builtin_amdgcn_mfma_f32_16x16x32_bf16(af[mi], bfr[ni], acc[mi][ni], 0, 0, 0);
  }

  size_t cbase = (size_t)blockIdx.z * sC;
#pragma unroll
  for (int mi = 0; mi < 4; mi++) {
#pragma unroll
    for (int ni = 0; ni < 4; ni++) {
      int gm = m0 + wm + mi * 16 + quad * 4;
      int gn = n0 + wn + ni * 16 + l16;
#pragma unroll
      for (int r = 0; r < 4; r++) {
        float val = acc[mi][ni][r];
        int m = gm + r;
        if (bias_mode == 1) val += bias[m];
        else if (bias_mode == 2) val += bias[gn];
        val *= scale;
        size_t idx = cbase + (size_t)m * N + gn;
        if (outF) outF[idx] = val + resid[idx];
        else outB[idx] = f2bf(val);
      }
    }
  }
}

// ---------------- row softmax in place on bf16 S (4096 cols) ----------------
__global__ __launch_bounds__(256) void softmax_rows(ushort_t* __restrict__ S) {
  uint4* p = (uint4*)(S + (size_t)blockIdx.x * 4096);
  int t = threadIdx.x;
  uint4 d0 = p[t * 2], d1 = p[t * 2 + 1];
  unsigned u[8] = {d0.x, d0.y, d0.z, d0.w, d1.x, d1.y, d1.z, d1.w};
  float v[16];
#pragma unroll
  for (int i = 0; i < 8; i++) {
    v[2 * i]     = __uint_as_float(u[i] << 16);
    v[2 * i + 1] = __uint_as_float(u[i] & 0xffff0000u);
  }
  float m = v[0];
#pragma unroll
  for (int i = 1; i < 16; i++) m = fmaxf(m, v[i]);
  for (int off = 32; off; off >>= 1) m = fmaxf(m, __shfl_xor(m, off, 64));
  __shared__ float sh[8];
  int wave = t >> 6, lane = t & 63;
  if (lane == 0) sh[wave] = m;
  __syncthreads();
  m = fmaxf(fmaxf(sh[0], sh[1]), fmaxf(sh[2], sh[3]));
  float sum = 0.f;
#pragma unroll
  for (int i = 0; i < 16; i++) { v[i] = __expf(v[i] - m); sum += v[i]; }
  for (int off = 32; off; off >>= 1) sum += __shfl_xor(sum, off, 64);
  if (lane == 0) sh[4 + wave] = sum;
  __syncthreads();
  float inv = 1.f / (sh[4] + sh[5] + sh[6] + sh[7]);
  unsigned o[8];
#pragma unroll
  for (int i = 0; i < 8; i++)
    o[i] = (unsigned)f2bf(v[2 * i] * inv) | ((unsigned)f2bf(v[2 * i + 1] * inv) << 16);
  p[t * 2]     = make_uint4(o[0], o[1], o[2], o[3]);
  p[t * 2 + 1] = make_uint4(o[4], o[5], o[6], o[7]);
}

extern "C" void kernel_launch(void* const* d_in, const int* in_sizes, int n_in,
                              void* d_out, int out_size, void* d_ws, size_t ws_size,
                              hipStream_t stream) {
  const float* x     = (const float*)d_in[0];
  const float* gamma = (const float*)d_in[1];
  const float* beta  = (const float*)d_in[2];
  const float* wq    = (const float*)d_in[3];
  const float* bq    = (const float*)d_in[4];
  const float* wk    = (const float*)d_in[5];
  const float* bk    = (const float*)d_in[6];
  const float* wv    = (const float*)d_in[7];
  const float* bv    = (const float*)d_in[8];
  const float* wo    = (const float*)d_in[9];
  const float* bo    = (const float*)d_in[10];
  float* out = (float*)d_out;

  // workspace layout (bf16 elements)
  ushort_t* wb  = (ushort_t*)d_ws;
  ushort_t* wqb = wb;
  ushort_t* wkb = wb + 262144;
  ushort_t* wvb = wb + 524288;
  ushort_t* wob = wb + 786432;
  ushort_t* hnT = wb + 1048576;        // 2 x 4096 x 512
  ushort_t* qT  = hnT + 4194304;       // 2 x 4096 x 512 (i,o)
  ushort_t* kT  = qT + 4194304;
  ushort_t* vC  = kT + 4194304;        // 2 x 512 x 4096 (c,i)
  ushort_t* OT  = vC + 4194304;        // 2 x 4096 x 512 (i,c)
  ushort_t* S   = OT + 4194304;        // 2 x 4096 x 4096
  float* stats  = (float*)(S + 33554432);  // 64 x (mean,rstd)

  const long long HS = 2097152;   // 4096*512 per batch
  const long long SS = 16777216;  // 4096*4096 per batch
  const float scale = 0.044194173824159216f;  // 512^-0.5

  cvt_weights<<<dim3(1024), dim3(256), 0, stream>>>(wq, wk, wv, wo, wb);
  gn_stats<<<dim3(64), dim3(256), 0, stream>>>(x, stats);
  gn_apply<<<dim3(128, 16, 2), dim3(32, 8), 0, stream>>>(x, gamma, beta, stats, hnT);
  // qT = hnT * wq^T  (M=4096,N=512,K=512), bias over n, x scale (folded)
  gemm_abt<<<dim3(4, 32, 2), dim3(256), 0, stream>>>(hnT, HS, wqb, 0, 512, 512, qT, HS, bq, 2, scale, nullptr, nullptr);
  // kT = hnT * wk^T
  gemm_abt<<<dim3(4, 32, 2), dim3(256), 0, stream>>>(hnT, HS, wkb, 0, 512, 512, kT, HS, bk, 2, 1.f, nullptr, nullptr);
  // v = wv * hnT^T  (M=512,N=4096,K=512), bias over m
  gemm_abt<<<dim3(32, 4, 2), dim3(256), 0, stream>>>(wvb, 0, hnT, HS, 512, 4096, vC, HS, bv, 1, 1.f, nullptr, nullptr);
  // S = qT * kT^T (M=N=4096, K=512), scale already in q
  gemm_abt<<<dim3(32, 32, 2), dim3(256), 0, stream>>>(qT, HS, kT, HS, 512, 4096, S, SS, nullptr, 0, 1.f, nullptr, nullptr);
  // softmax rows (8192 rows over both batches)
  softmax_rows<<<dim3(8192), dim3(256), 0, stream>>>(S);
  // OT = P * v^T (M=4096, N=512, K=4096)
  gemm_abt<<<dim3(4, 32, 2), dim3(256), 0, stream>>>(S, SS, vC, HS, 4096, 512, OT, HS, nullptr, 0, 1.f, nullptr, nullptr);
  // y = wo * OT^T + bo + x (M=512, N=4096, K=512), fp32 out with residual
  gemm_abt<<<dim3(32, 4, 2), dim3(256), 0, stream>>>(wob, 0, OT, HS, 512, 4096, nullptr, HS, bo, 1, 1.f, out, x);
}

// Round 3
// 385.299 us; speedup vs baseline: 1.1073x; 1.0799x over previous
//
#include <hip/hip_runtime.h>

typedef unsigned short ushort_t;
typedef __bf16 bf16x8 __attribute__((ext_vector_type(8)));
typedef float f32x4 __attribute__((ext_vector_type(4)));

__device__ __forceinline__ ushort_t f2bf(float f) {
  unsigned u = __float_as_uint(f);
  u += 0x7fff + ((u >> 16) & 1);
  return (ushort_t)(u >> 16);
}

// async global -> LDS, 16B per lane (wave stages 1024B contiguous)
__device__ __forceinline__ void gload16(const void* g, void* l) {
  __builtin_amdgcn_global_load_lds(
      (const __attribute__((address_space(1))) unsigned int*)g,
      (__attribute__((address_space(3))) unsigned int*)l, 16, 0, 0);
}

// ---------------- weight fp32 -> bf16 ----------------
__global__ __launch_bounds__(256) void cvt_weights(
    const float* __restrict__ wq, const float* __restrict__ wk,
    const float* __restrict__ wv, const float* __restrict__ wo,
    ushort_t* __restrict__ dst) {
  int i = blockIdx.x * 256 + threadIdx.x;  // 262144 per matrix
  dst[i]          = f2bf(wq[i]);
  dst[262144 + i] = f2bf(wk[i]);
  dst[524288 + i] = f2bf(wv[i]);
  dst[786432 + i] = f2bf(wo[i]);
}

// ---------------- zero the rowsum accumulator ----------------
__global__ __launch_bounds__(256) void zero_f32(float* __restrict__ p) {
  p[blockIdx.x * 256 + threadIdx.x] = 0.f;
}

// ---------------- group norm stats: one block per (b,g) ----------------
__global__ __launch_bounds__(256) void gn_stats(const float* __restrict__ x,
                                                float* __restrict__ stats) {
  const float4* p = (const float4*)(x + (size_t)blockIdx.x * 65536);
  float s = 0.f, ss = 0.f;
  for (int i = threadIdx.x; i < 16384; i += 256) {
    float4 v = p[i];
    s += v.x + v.y + v.z + v.w;
    ss += v.x * v.x + v.y * v.y + v.z * v.z + v.w * v.w;
  }
  for (int off = 32; off; off >>= 1) {
    s += __shfl_xor(s, off, 64);
    ss += __shfl_xor(ss, off, 64);
  }
  __shared__ float sh[8];
  int wave = threadIdx.x >> 6, lane = threadIdx.x & 63;
  if (lane == 0) { sh[wave] = s; sh[4 + wave] = ss; }
  __syncthreads();
  if (threadIdx.x == 0) {
    s = sh[0] + sh[1] + sh[2] + sh[3];
    ss = sh[4] + sh[5] + sh[6] + sh[7];
    float mean = s * (1.f / 65536.f);
    float var = ss * (1.f / 65536.f) - mean * mean;
    stats[blockIdx.x * 2] = mean;
    stats[blockIdx.x * 2 + 1] = rsqrtf(var + 1e-6f);
  }
}

// ---------------- GN apply + transpose: x (b,c,n) -> hnT (b,n,c) bf16 ----------------
__global__ __launch_bounds__(256) void gn_apply(
    const float* __restrict__ x, const float* __restrict__ gamma,
    const float* __restrict__ beta, const float* __restrict__ stats,
    ushort_t* __restrict__ hnT) {
  __shared__ float T[32][33];
  int i0 = blockIdx.x * 32, c0 = blockIdx.y * 32, b = blockIdx.z;
  int tx = threadIdx.x, ty = threadIdx.y;  // (32,8)
#pragma unroll
  for (int k = 0; k < 4; k++) {
    int cl = ty + k * 8;
    int c = c0 + cl;
    int bg = (b * 32 + (c >> 4)) * 2;
    float mean = stats[bg], rstd = stats[bg + 1];
    float v = x[((size_t)(b * 512 + c)) * 4096 + i0 + tx];
    T[cl][tx] = (v - mean) * rstd * gamma[c] + beta[c];
  }
  __syncthreads();
#pragma unroll
  for (int k = 0; k < 4; k++) {
    int il = ty + k * 8;
    hnT[((size_t)b * 4096 + i0 + il) * 512 + c0 + tx] = f2bf(T[tx][il]);
  }
}

// ---------------- generic C = A * B^T GEMM (bf16 in, fp32 acc) ----------------
// A: M x K row-major (per-batch stride sA), B: N x K row-major (stride sB)
// Epilogue: val = acc; if colscale: val/=cs[col]; += bias; *= scale;
//           if rowsum: val=exp(val), atomic row-sums into rowsum[]
// Single-barrier double-buffered global_load_lds pipeline.
__global__ __launch_bounds__(256) void gemm_abt(
    const ushort_t* __restrict__ A, long long sA,
    const ushort_t* __restrict__ B, long long sB,
    int K, int N,
    ushort_t* __restrict__ outB, long long sC,
    const float* __restrict__ bias, int bias_mode, float scale,
    float* __restrict__ outF, const float* __restrict__ resid,
    float* __restrict__ rowsum, const float* __restrict__ colscale) {
  __shared__ __align__(16) ushort_t As[2][128][32];  // 16 KB
  __shared__ __align__(16) ushort_t Bs[2][128][32];  // 16 KB
  const ushort_t* Ab = A + (size_t)blockIdx.z * sA;
  const ushort_t* Bb = B + (size_t)blockIdx.z * sB;
  int m0 = blockIdx.y * 128, n0 = blockIdx.x * 128;
  int t = threadIdx.x;
  int lane = t & 63;
  int quad = lane >> 4, l16 = lane & 15;
  int wave = t >> 6;
  int wm = (wave >> 1) * 64, wn = (wave & 1) * 64;

  f32x4 acc[4][4];
#pragma unroll
  for (int i = 0; i < 4; i++)
#pragma unroll
    for (int j = 0; j < 4; j++)
#pragma unroll
      for (int r = 0; r < 4; r++) acc[i][j][r] = 0.f;

  // staging: wave w stages chunks {2w, 2w+1}; chunk = 16 rows x 32 cols.
  int chunk = wave * 2;
  int srow = chunk * 16 + (lane >> 2);
  int skoff = (lane & 3) * 8;
  const ushort_t* gA0 = Ab + (size_t)(m0 + srow) * K + skoff;
  const ushort_t* gA1 = gA0 + (size_t)16 * K;
  const ushort_t* gB0 = Bb + (size_t)(n0 + srow) * K + skoff;
  const ushort_t* gB1 = gB0 + (size_t)16 * K;
  char* lA = (char*)&As[0][0][0] + chunk * 1024 + lane * 16;
  char* lB = (char*)&Bs[0][0][0] + chunk * 1024 + lane * 16;

  // prologue: tile 0 -> buffer 0
  gload16(gA0, lA);
  gload16(gA1, lA + 1024);
  gload16(gB0, lB);
  gload16(gB1, lB + 1024);

  for (int k0 = 0; k0 < K; k0 += 32) {
    int p = (k0 >> 5) & 1;
    __syncthreads();  // vmcnt(0) drain: buffer p's loads complete; prev compute done
    if (k0 + 32 < K) {
      int pofs = (p ^ 1) * 8192;
      gload16(gA0 + k0 + 32, lA + pofs);
      gload16(gA1 + k0 + 32, lA + pofs + 1024);
      gload16(gB0 + k0 + 32, lB + pofs);
      gload16(gB1 + k0 + 32, lB + pofs + 1024);
    }
    bf16x8 af[4], bfr[4];
#pragma unroll
    for (int i = 0; i < 4; i++) {
      af[i]  = *(const bf16x8*)&As[p][wm + i * 16 + l16][quad * 8];
      bfr[i] = *(const bf16x8*)&Bs[p][wn + i * 16 + l16][quad * 8];
    }
#pragma unroll
    for (int mi = 0; mi < 4; mi++)
#pragma unroll
      for (int ni = 0; ni < 4; ni++)
        acc[mi][ni] = __builtin_amdgcn_mfma_f32_16x16x32_bf16(af[mi], bfr[ni], acc[mi][ni], 0, 0, 0);
  }

  size_t cbase = (size_t)blockIdx.z * sC;
  float cs[4];
  if (colscale) {
#pragma unroll
    for (int ni = 0; ni < 4; ni++)
      cs[ni] = 1.0f / colscale[(size_t)blockIdx.z * N + n0 + wn + ni * 16 + l16];
  }
#pragma unroll
  for (int mi = 0; mi < 4; mi++) {
#pragma unroll
    for (int r = 0; r < 4; r++) {
      int m = m0 + wm + mi * 16 + quad * 4 + r;
      float rs = 0.f;
#pragma unroll
      for (int ni = 0; ni < 4; ni++) {
        float val = acc[mi][ni][r];
        int gn = n0 + wn + ni * 16 + l16;
        if (colscale) val *= cs[ni];
        if (bias_mode == 1) val += bias[m];
        else if (bias_mode == 2) val += bias[gn];
        val *= scale;
        if (rowsum) { val = __expf(val); rs += val; }
        size_t idx = cbase + (size_t)m * N + gn;
        if (outF) outF[idx] = val + resid[idx];
        else outB[idx] = f2bf(val);
      }
      if (rowsum) {
        rs += __shfl_xor(rs, 1, 64);
        rs += __shfl_xor(rs, 2, 64);
        rs += __shfl_xor(rs, 4, 64);
        rs += __shfl_xor(rs, 8, 64);
        if (l16 == 0) atomicAdd(&rowsum[(size_t)blockIdx.z * 4096 + m], rs);
      }
    }
  }
}

extern "C" void kernel_launch(void* const* d_in, const int* in_sizes, int n_in,
                              void* d_out, int out_size, void* d_ws, size_t ws_size,
                              hipStream_t stream) {
  const float* x     = (const float*)d_in[0];
  const float* gamma = (const float*)d_in[1];
  const float* beta  = (const float*)d_in[2];
  const float* wq    = (const float*)d_in[3];
  const float* bq    = (const float*)d_in[4];
  const float* wk    = (const float*)d_in[5];
  const float* bk    = (const float*)d_in[6];
  const float* wv    = (const float*)d_in[7];
  const float* bv    = (const float*)d_in[8];
  const float* wo    = (const float*)d_in[9];
  const float* bo    = (const float*)d_in[10];
  float* out = (float*)d_out;

  // workspace layout (bf16 elements)
  ushort_t* wb  = (ushort_t*)d_ws;
  ushort_t* wqb = wb;
  ushort_t* wkb = wb + 262144;
  ushort_t* wvb = wb + 524288;
  ushort_t* wob = wb + 786432;
  ushort_t* hnT = wb + 1048576;        // 2 x 4096 x 512
  ushort_t* qT  = hnT + 4194304;       // 2 x 4096 x 512 (i,o)
  ushort_t* kT  = qT + 4194304;
  ushort_t* vC  = kT + 4194304;        // 2 x 512 x 4096 (c,i)
  ushort_t* OT  = vC + 4194304;        // 2 x 4096 x 512 (i,c)
  ushort_t* S   = OT + 4194304;        // 2 x 4096 x 4096 (holds P = exp(S))
  float* stats  = (float*)(S + 33554432);  // 64 x (mean,rstd)
  float* l      = (float*)hnT;         // 2 x 4096 row sums (hnT dead after v-GEMM)

  const long long HS = 2097152;   // 4096*512 per batch
  const long long SS = 16777216;  // 4096*4096 per batch
  const float scale = 0.044194173824159216f;  // 512^-0.5

  cvt_weights<<<dim3(1024), dim3(256), 0, stream>>>(wq, wk, wv, wo, wb);
  gn_stats<<<dim3(64), dim3(256), 0, stream>>>(x, stats);
  gn_apply<<<dim3(128, 16, 2), dim3(32, 8), 0, stream>>>(x, gamma, beta, stats, hnT);
  // qT = hnT * wq^T  (M=4096,N=512,K=512), bias over n, x scale (folded)
  gemm_abt<<<dim3(4, 32, 2), dim3(256), 0, stream>>>(hnT, HS, wqb, 0, 512, 512, qT, HS, bq, 2, scale, nullptr, nullptr, nullptr, nullptr);
  // kT = hnT * wk^T
  gemm_abt<<<dim3(4, 32, 2), dim3(256), 0, stream>>>(hnT, HS, wkb, 0, 512, 512, kT, HS, bk, 2, 1.f, nullptr, nullptr, nullptr, nullptr);
  // v = wv * hnT^T  (M=512,N=4096,K=512), bias over m
  gemm_abt<<<dim3(32, 4, 2), dim3(256), 0, stream>>>(wvb, 0, hnT, HS, 512, 4096, vC, HS, bv, 1, 1.f, nullptr, nullptr, nullptr, nullptr);
  // hnT dead; reuse as rowsum l (zero it)
  zero_f32<<<dim3(32), dim3(256), 0, stream>>>(l);
  // P = exp(qT * kT^T) with fused row sums (M=N=4096, K=512; scale folded in q)
  gemm_abt<<<dim3(32, 32, 2), dim3(256), 0, stream>>>(qT, HS, kT, HS, 512, 4096, S, SS, nullptr, 0, 1.f, nullptr, nullptr, l, nullptr);
  // OT = P * v^T (M=4096, N=512, K=4096), unnormalized
  gemm_abt<<<dim3(4, 32, 2), dim3(256), 0, stream>>>(S, SS, vC, HS, 4096, 512, OT, HS, nullptr, 0, 1.f, nullptr, nullptr, nullptr, nullptr);
  // y = wo * (OT/l)^T + bo + x (M=512, N=4096, K=512), fp32 out, col-normalized
  gemm_abt<<<dim3(32, 4, 2), dim3(256), 0, stream>>>(wob, 0, OT, HS, 512, 4096, nullptr, HS, bo, 1, 1.f, out, x, nullptr, l);
}

// Round 4
// 332.115 us; speedup vs baseline: 1.2846x; 1.1601x over previous
//
#include <hip/hip_runtime.h>

typedef unsigned short ushort_t;
typedef __bf16 bf16x8 __attribute__((ext_vector_type(8)));
typedef float f32x4 __attribute__((ext_vector_type(4)));

__device__ __forceinline__ ushort_t f2bf(float f) {
  unsigned u = __float_as_uint(f);
  u += 0x7fff + ((u >> 16) & 1);
  return (ushort_t)(u >> 16);
}

__device__ __forceinline__ void gload16(const void* g, void* l) {
  __builtin_amdgcn_global_load_lds(
      (const __attribute__((address_space(1))) unsigned int*)g,
      (__attribute__((address_space(3))) unsigned int*)l, 16, 0, 0);
}

// ---------------- weight fp32 -> bf16, pack qk bias, zero stats2 ----------------
__global__ __launch_bounds__(256) void cvt_weights(
    const float* __restrict__ wq, const float* __restrict__ wk,
    const float* __restrict__ wv, const float* __restrict__ wo,
    const float* __restrict__ bq, const float* __restrict__ bk,
    ushort_t* __restrict__ dst, float* __restrict__ qkbias,
    float* __restrict__ stats2) {
  int b = blockIdx.x, t = threadIdx.x;
  if (b < 1024) {
    int i = b * 256 + t;
    dst[i]          = f2bf(wq[i]);
    dst[262144 + i] = f2bf(wk[i]);
    dst[524288 + i] = f2bf(wv[i]);
    dst[786432 + i] = f2bf(wo[i]);
  } else if (b < 1028) {
    int j = (b - 1024) * 256 + t;  // 0..1023
    qkbias[j] = (j < 512) ? bq[j] : bk[j - 512];
  } else {
    if (t < 128) stats2[t] = 0.f;
  }
}

// ---------------- zero the rowsum accumulator ----------------
__global__ __launch_bounds__(256) void zero_f32(float* __restrict__ p) {
  p[blockIdx.x * 256 + threadIdx.x] = 0.f;
}

// ---------------- group norm partial stats: 4 blocks per (b,g) ----------------
__global__ __launch_bounds__(256) void gn_stats_partial(const float* __restrict__ x,
                                                        float* __restrict__ stats2) {
  int bg = blockIdx.x >> 2, q = blockIdx.x & 3;
  const float4* p = (const float4*)(x + (size_t)bg * 65536 + q * 16384);
  float s = 0.f, ss = 0.f;
  for (int i = threadIdx.x; i < 4096; i += 256) {
    float4 v = p[i];
    s += v.x + v.y + v.z + v.w;
    ss += v.x * v.x + v.y * v.y + v.z * v.z + v.w * v.w;
  }
  for (int off = 32; off; off >>= 1) {
    s += __shfl_xor(s, off, 64);
    ss += __shfl_xor(ss, off, 64);
  }
  __shared__ float sh[8];
  int wave = threadIdx.x >> 6, lane = threadIdx.x & 63;
  if (lane == 0) { sh[wave] = s; sh[4 + wave] = ss; }
  __syncthreads();
  if (threadIdx.x == 0) {
    atomicAdd(&stats2[bg * 2], sh[0] + sh[1] + sh[2] + sh[3]);
    atomicAdd(&stats2[bg * 2 + 1], sh[4] + sh[5] + sh[6] + sh[7]);
  }
}

__global__ __launch_bounds__(64) void gn_finalize(const float* __restrict__ stats2,
                                                  float* __restrict__ stats) {
  int t = threadIdx.x;  // 64 groups total (2 batches x 32)
  float s = stats2[t * 2], ss = stats2[t * 2 + 1];
  float mean = s * (1.f / 65536.f);
  float var = ss * (1.f / 65536.f) - mean * mean;
  stats[t * 2] = mean;
  stats[t * 2 + 1] = rsqrtf(var + 1e-6f);
}

// ---------------- GN apply + transpose: x (b,c,n) -> hnT (b,n,c) bf16 ----------------
__global__ __launch_bounds__(256) void gn_apply(
    const float* __restrict__ x, const float* __restrict__ gamma,
    const float* __restrict__ beta, const float* __restrict__ stats,
    ushort_t* __restrict__ hnT) {
  __shared__ float T[32][33];
  int i0 = blockIdx.x * 32, c0 = blockIdx.y * 32, b = blockIdx.z;
  int tx = threadIdx.x, ty = threadIdx.y;  // (32,8)
#pragma unroll
  for (int k = 0; k < 4; k++) {
    int cl = ty + k * 8;
    int c = c0 + cl;
    int bg = (b * 32 + (c >> 4)) * 2;
    float mean = stats[bg], rstd = stats[bg + 1];
    float v = x[((size_t)(b * 512 + c)) * 4096 + i0 + tx];
    T[cl][tx] = (v - mean) * rstd * gamma[c] + beta[c];
  }
  __syncthreads();
#pragma unroll
  for (int k = 0; k < 4; k++) {
    int il = ty + k * 8;
    hnT[((size_t)b * 4096 + i0 + il) * 512 + c0 + tx] = f2bf(T[tx][il]);
  }
}

// ---------------- C = A * B^T GEMM, 128 x BN tile, bf16 in / fp32 acc ----------------
// A: M x K rows (row stride lda, batch stride sA); B: N x K (ldb, sB).
// epilogue: val = acc; /= colscale[col]; += bias; *= scale; exp+rowsum; store.
// single-barrier double-buffered global_load_lds pipeline.
template <int BN>
__global__ __launch_bounds__(256) void gemm_abt(
    const ushort_t* __restrict__ A, long long sA, int lda,
    const ushort_t* __restrict__ B, long long sB, int ldb,
    int K, int N, int ldc,
    ushort_t* __restrict__ outB, long long sC,
    const float* __restrict__ bias, int bias_mode, float scale,
    float* __restrict__ outF, const float* __restrict__ resid,
    float* __restrict__ rowsum, const float* __restrict__ colscale) {
  constexpr int BCH = BN / 16;        // B chunks (chunk = 16 rows x 32 cols)
  constexpr int CH = 8 + BCH;
  constexpr int CPW = CH / 4;         // chunks per wave
  constexpr int SB = (128 + BN) * 32; // elements per LDS buffer
  constexpr int MI = (BN == 128) ? 4 : 2;
  constexpr int NI = 4;
  __shared__ __align__(16) ushort_t Ls[2][SB];

  const ushort_t* Ab = A + (size_t)blockIdx.z * sA;
  const ushort_t* Bb = B + (size_t)blockIdx.z * sB;
  int m0 = blockIdx.y * 128, n0 = blockIdx.x * BN;
  int t = threadIdx.x;
  int lane = t & 63;
  int quad = lane >> 4, l16 = lane & 15;
  int wave = t >> 6;
  int wm = (BN == 128) ? (wave >> 1) * 64 : wave * 32;
  int wn = (BN == 128) ? (wave & 1) * 64 : 0;

  f32x4 acc[MI][NI];
#pragma unroll
  for (int i = 0; i < MI; i++)
#pragma unroll
    for (int j = 0; j < NI; j++)
#pragma unroll
      for (int r = 0; r < 4; r++) acc[i][j][r] = 0.f;

  // staging pointers
  const ushort_t* gp[CPW];
  int lofs[CPW];  // byte offset within one LDS buffer
  int crow = lane >> 2, skoff = (lane & 3) * 8;
#pragma unroll
  for (int i = 0; i < CPW; i++) {
    int c = wave * CPW + i;
    if (c < 8) {
      gp[i] = Ab + (size_t)(m0 + c * 16 + crow) * lda + skoff;
      lofs[i] = c * 1024 + lane * 16;
    } else {
      int cb = c - 8;
      gp[i] = Bb + (size_t)(n0 + cb * 16 + crow) * ldb + skoff;
      lofs[i] = 8192 + cb * 1024 + lane * 16;
    }
  }
  char* lbase = (char*)&Ls[0][0];

  // prologue: tile 0 -> buffer 0
#pragma unroll
  for (int i = 0; i < CPW; i++) gload16(gp[i], lbase + lofs[i]);

  for (int k0 = 0; k0 < K; k0 += 32) {
    int p = (k0 >> 5) & 1;
    __syncthreads();  // drains buffer-p loads; prev compute done
    if (k0 + 32 < K) {
      int pofs = (p ^ 1) * (SB * 2);
#pragma unroll
      for (int i = 0; i < CPW; i++) gload16(gp[i] + k0 + 32, lbase + pofs + lofs[i]);
    }
    bf16x8 af[MI], bfr[NI];
#pragma unroll
    for (int i = 0; i < MI; i++)
      af[i] = *(const bf16x8*)&Ls[p][(wm + i * 16 + l16) * 32 + quad * 8];
#pragma unroll
    for (int j = 0; j < NI; j++)
      bfr[j] = *(const bf16x8*)&Ls[p][4096 + (wn + j * 16 + l16) * 32 + quad * 8];
#pragma unroll
    for (int mi = 0; mi < MI; mi++)
#pragma unroll
      for (int ni = 0; ni < NI; ni++)
        acc[mi][ni] = __builtin_amdgcn_mfma_f32_16x16x32_bf16(af[mi], bfr[ni], acc[mi][ni], 0, 0, 0);
  }

  size_t cbase = (size_t)blockIdx.z * sC;
  float cs[NI];
  if (colscale) {
#pragma unroll
    for (int ni = 0; ni < NI; ni++)
      cs[ni] = 1.0f / colscale[(size_t)blockIdx.z * N + n0 + wn + ni * 16 + l16];
  }
#pragma unroll
  for (int mi = 0; mi < MI; mi++) {
#pragma unroll
    for (int r = 0; r < 4; r++) {
      int m = m0 + wm + mi * 16 + quad * 4 + r;
      float rs = 0.f;
#pragma unroll
      for (int ni = 0; ni < NI; ni++) {
        float val = acc[mi][ni][r];
        int gn = n0 + wn + ni * 16 + l16;
        if (colscale) val *= cs[ni];
        if (bias_mode == 1) val += bias[m];
        else if (bias_mode == 2) val += bias[gn];
        val *= scale;
        if (rowsum) { val = __expf(val); rs += val; }
        size_t idx = cbase + (size_t)m * ldc + gn;
        if (outF) outF[idx] = val + resid[idx];
        else outB[idx] = f2bf(val);
      }
      if (rowsum) {
        rs += __shfl_xor(rs, 1, 64);
        rs += __shfl_xor(rs, 2, 64);
        rs += __shfl_xor(rs, 4, 64);
        rs += __shfl_xor(rs, 8, 64);
        if (l16 == 0) atomicAdd(&rowsum[(size_t)blockIdx.z * 4096 + m], rs);
      }
    }
  }
}

extern "C" void kernel_launch(void* const* d_in, const int* in_sizes, int n_in,
                              void* d_out, int out_size, void* d_ws, size_t ws_size,
                              hipStream_t stream) {
  const float* x     = (const float*)d_in[0];
  const float* gamma = (const float*)d_in[1];
  const float* beta  = (const float*)d_in[2];
  const float* wq    = (const float*)d_in[3];
  const float* bq    = (const float*)d_in[4];
  const float* wk    = (const float*)d_in[5];
  const float* bk    = (const float*)d_in[6];
  const float* wv    = (const float*)d_in[7];
  const float* bv    = (const float*)d_in[8];
  const float* wo    = (const float*)d_in[9];
  const float* bo    = (const float*)d_in[10];
  float* out = (float*)d_out;

  // workspace layout (bf16 elements)
  ushort_t* wb  = (ushort_t*)d_ws;     // [wq;wk] 1024x512, wv, wo
  ushort_t* wvb = wb + 524288;
  ushort_t* wob = wb + 786432;
  ushort_t* hnT = wb + 1048576;        // 2 x 4096 x 512
  ushort_t* qkT = hnT + 4194304;       // 2 x 4096 x 1024 (q cols 0-511, k cols 512-1023)
  ushort_t* vC  = qkT + 8388608;       // 2 x 512 x 4096
  ushort_t* OT  = vC + 4194304;        // 2 x 4096 x 512
  ushort_t* S   = OT + 4194304;        // 2 x 4096 x 4096 (holds P = exp(scale*S))
  float* fbuf   = (float*)(S + 33554432);
  float* stats  = fbuf;                // 128
  float* stats2 = fbuf + 128;          // 128
  float* qkbias = fbuf + 256;          // 1024
  float* l      = (float*)hnT;         // 2 x 4096 row sums (hnT dead after v-GEMM)

  const long long HS = 2097152;   // 4096*512 per batch
  const long long QS = 4194304;   // 4096*1024 per batch
  const long long SS = 16777216;  // 4096*4096 per batch
  const float scale = 0.044194173824159216f;  // 512^-0.5

  cvt_weights<<<dim3(1029), dim3(256), 0, stream>>>(wq, wk, wv, wo, bq, bk, wb, qkbias, stats2);
  gn_stats_partial<<<dim3(256), dim3(256), 0, stream>>>(x, stats2);
  gn_finalize<<<dim3(1), dim3(64), 0, stream>>>(stats2, stats);
  gn_apply<<<dim3(128, 16, 2), dim3(32, 8), 0, stream>>>(x, gamma, beta, stats, hnT);
  // qkT = hnT * [wq;wk]^T  (M=4096, N=1024, K=512), packed col bias
  gemm_abt<128><<<dim3(8, 32, 2), dim3(256), 0, stream>>>(
      hnT, HS, 512, wb, 0, 512, 512, 1024, 1024, qkT, QS, qkbias, 2, 1.f,
      nullptr, nullptr, nullptr, nullptr);
  // vC = wv * hnT^T  (M=512, N=4096, K=512), row bias
  gemm_abt<64><<<dim3(64, 4, 2), dim3(256), 0, stream>>>(
      wvb, 0, 512, hnT, HS, 512, 512, 4096, 4096, vC, HS, bv, 1, 1.f,
      nullptr, nullptr, nullptr, nullptr);
  // hnT dead; reuse as rowsum l
  zero_f32<<<dim3(32), dim3(256), 0, stream>>>(l);
  // P = exp(scale * q*k^T) with fused row sums (M=N=4096, K=512)
  gemm_abt<128><<<dim3(32, 32, 2), dim3(256), 0, stream>>>(
      qkT, QS, 1024, qkT + 512, QS, 1024, 512, 4096, 4096, S, SS, nullptr, 0, scale,
      nullptr, nullptr, l, nullptr);
  // OT = P * vC^T (M=4096, N=512, K=4096), unnormalized
  gemm_abt<64><<<dim3(8, 32, 2), dim3(256), 0, stream>>>(
      S, SS, 4096, vC, HS, 4096, 4096, 512, 512, OT, HS, nullptr, 0, 1.f,
      nullptr, nullptr, nullptr, nullptr);
  // y = wo * (OT/l)^T + bo + x (M=512, N=4096, K=512), fp32 out + residual
  gemm_abt<64><<<dim3(64, 4, 2), dim3(256), 0, stream>>>(
      wob, 0, 512, OT, HS, 512, 512, 4096, 4096, nullptr, HS, bo, 1, 1.f,
      out, x, nullptr, l);
}

// Round 5
// 286.758 us; speedup vs baseline: 1.4878x; 1.1582x over previous
//
#include <hip/hip_runtime.h>

typedef unsigned short ushort_t;
typedef __bf16 bf16x8 __attribute__((ext_vector_type(8)));
typedef float f32x4 __attribute__((ext_vector_type(4)));

__device__ __forceinline__ ushort_t f2bf(float f) {
  unsigned u = __float_as_uint(f);
  u += 0x7fff + ((u >> 16) & 1);
  return (ushort_t)(u >> 16);
}

__device__ __forceinline__ void gload16(const void* g, void* l) {
  __builtin_amdgcn_global_load_lds(
      (const __attribute__((address_space(1))) unsigned int*)g,
      (__attribute__((address_space(3))) unsigned int*)l, 16, 0, 0);
}

// ---------------- weight fp32 -> bf16, pack qk bias, zero stats2 ----------------
__global__ __launch_bounds__(256) void cvt_weights(
    const float* __restrict__ wq, const float* __restrict__ wk,
    const float* __restrict__ wv, const float* __restrict__ wo,
    const float* __restrict__ bq, const float* __restrict__ bk,
    ushort_t* __restrict__ dst, float* __restrict__ qkbias,
    float* __restrict__ stats2) {
  int b = blockIdx.x, t = threadIdx.x;
  if (b < 1024) {
    int i = b * 256 + t;
    dst[i]          = f2bf(wq[i]);
    dst[262144 + i] = f2bf(wk[i]);
    dst[524288 + i] = f2bf(wv[i]);
    dst[786432 + i] = f2bf(wo[i]);
  } else if (b < 1028) {
    int j = (b - 1024) * 256 + t;  // 0..1023
    qkbias[j] = (j < 512) ? bq[j] : bk[j - 512];
  } else {
    if (t < 128) stats2[t] = 0.f;
  }
}

// ---------------- zero the rowsum accumulator ----------------
__global__ __launch_bounds__(256) void zero_f32(float* __restrict__ p) {
  p[blockIdx.x * 256 + threadIdx.x] = 0.f;
}

// ---------------- group norm partial stats: 4 blocks per (b,g) ----------------
__global__ __launch_bounds__(256) void gn_stats_partial(const float* __restrict__ x,
                                                        float* __restrict__ stats2) {
  int bg = blockIdx.x >> 2, q = blockIdx.x & 3;
  const float4* p = (const float4*)(x + (size_t)bg * 65536 + q * 16384);
  float s = 0.f, ss = 0.f;
  for (int i = threadIdx.x; i < 4096; i += 256) {
    float4 v = p[i];
    s += v.x + v.y + v.z + v.w;
    ss += v.x * v.x + v.y * v.y + v.z * v.z + v.w * v.w;
  }
  for (int off = 32; off; off >>= 1) {
    s += __shfl_xor(s, off, 64);
    ss += __shfl_xor(ss, off, 64);
  }
  __shared__ float sh[8];
  int wave = threadIdx.x >> 6, lane = threadIdx.x & 63;
  if (lane == 0) { sh[wave] = s; sh[4 + wave] = ss; }
  __syncthreads();
  if (threadIdx.x == 0) {
    atomicAdd(&stats2[bg * 2], sh[0] + sh[1] + sh[2] + sh[3]);
    atomicAdd(&stats2[bg * 2 + 1], sh[4] + sh[5] + sh[6] + sh[7]);
  }
}

__global__ __launch_bounds__(64) void gn_finalize(const float* __restrict__ stats2,
                                                  float* __restrict__ stats) {
  int t = threadIdx.x;  // 64 groups total (2 batches x 32)
  float s = stats2[t * 2], ss = stats2[t * 2 + 1];
  float mean = s * (1.f / 65536.f);
  float var = ss * (1.f / 65536.f) - mean * mean;
  stats[t * 2] = mean;
  stats[t * 2 + 1] = rsqrtf(var + 1e-6f);
}

// ---------------- GN apply + transpose: x (b,c,n) -> hnT (b,n,c) bf16 ----------------
__global__ __launch_bounds__(256) void gn_apply(
    const float* __restrict__ x, const float* __restrict__ gamma,
    const float* __restrict__ beta, const float* __restrict__ stats,
    ushort_t* __restrict__ hnT) {
  __shared__ float T[32][33];
  int i0 = blockIdx.x * 32, c0 = blockIdx.y * 32, b = blockIdx.z;
  int tx = threadIdx.x, ty = threadIdx.y;  // (32,8)
#pragma unroll
  for (int k = 0; k < 4; k++) {
    int cl = ty + k * 8;
    int c = c0 + cl;
    int bg = (b * 32 + (c >> 4)) * 2;
    float mean = stats[bg], rstd = stats[bg + 1];
    float v = x[((size_t)(b * 512 + c)) * 4096 + i0 + tx];
    T[cl][tx] = (v - mean) * rstd * gamma[c] + beta[c];
  }
  __syncthreads();
#pragma unroll
  for (int k = 0; k < 4; k++) {
    int il = ty + k * 8;
    hnT[((size_t)b * 4096 + i0 + il) * 512 + c0 + tx] = f2bf(T[tx][il]);
  }
}

// ---------------- C = A * B^T GEMM, 128 x BN tile, bf16 in / fp32 acc ----------------
// B rows are staged into LDS with the in-window permutation slot s -> row
// (s&15)*4 + (s>>4), so lane l16's NI=4 accumulators cover 4 CONSECUTIVE output
// columns -> packed 8B/16B stores. Single-barrier double-buffered global_load_lds.
// swiz: remap blocks so same-A-row blocks share an XCD (id%8 heuristic).
template <int BN>
__global__ __launch_bounds__(256) void gemm_abt(
    const ushort_t* __restrict__ A, long long sA, int lda,
    const ushort_t* __restrict__ B, long long sB, int ldb,
    int K, int N, int ldc,
    ushort_t* __restrict__ outB, long long sC,
    const float* __restrict__ bias, int bias_mode, float scale,
    float* __restrict__ outF, const float* __restrict__ resid,
    float* __restrict__ rowsum, const float* __restrict__ colscale, int swiz) {
  constexpr int BCH = BN / 16;        // B chunks (chunk = 16 rows x 32 cols)
  constexpr int CPW = (8 + BCH) / 4;  // chunks per wave
  constexpr int SB = (128 + BN) * 32; // elements per LDS buffer
  constexpr int MI = (BN == 128) ? 4 : 2;
  constexpr int NI = 4;
  __shared__ __align__(16) ushort_t Ls[2][SB];

  int bx = blockIdx.x, by = blockIdx.y, bz = blockIdx.z;
  if (swiz) {
    unsigned nx = gridDim.x, ny = gridDim.y;
    unsigned id = (blockIdx.z * ny + blockIdx.y) * nx + blockIdx.x;
    unsigned pb8 = (nx * ny) >> 3;   // per-batch blocks / 8
    unsigned c = id & 7, j = id >> 3;
    bz = j / pb8;
    unsigned jb = j - bz * pb8;
    unsigned jy = jb / nx;
    by = c * (ny >> 3) + jy;
    bx = jb - jy * nx;
  }

  const ushort_t* Ab = A + (size_t)bz * sA;
  const ushort_t* Bb = B + (size_t)bz * sB;
  int m0 = by * 128, n0 = bx * BN;
  int t = threadIdx.x;
  int lane = t & 63;
  int quad = lane >> 4, l16 = lane & 15;
  int wave = t >> 6;
  int wm = (BN == 128) ? (wave >> 1) * 64 : wave * 32;
  int wn = (BN == 128) ? (wave & 1) * 64 : 0;

  f32x4 acc[MI][NI];
#pragma unroll
  for (int i = 0; i < MI; i++)
#pragma unroll
    for (int j = 0; j < NI; j++)
#pragma unroll
      for (int r = 0; r < 4; r++) acc[i][j][r] = 0.f;

  // staging pointers
  const ushort_t* gp[CPW];
  int lofs[CPW];  // byte offset within one LDS buffer
  int crow = lane >> 2, skoff = (lane & 3) * 8;
#pragma unroll
  for (int i = 0; i < CPW; i++) {
    int c = wave * CPW + i;
    if (c < 8) {
      gp[i] = Ab + (size_t)(m0 + c * 16 + crow) * lda + skoff;
      lofs[i] = c * 1024 + lane * 16;
    } else {
      int slot = (c - 8) * 16 + crow;  // LDS slot in [0, BN)
      int arow = (slot & ~63) + ((slot & 15) * 4) + ((slot & 63) >> 4);
      gp[i] = Bb + (size_t)(n0 + arow) * ldb + skoff;
      lofs[i] = 8192 + (c - 8) * 1024 + lane * 16;
    }
  }
  char* lbase = (char*)&Ls[0][0];

  // prologue: tile 0 -> buffer 0
#pragma unroll
  for (int i = 0; i < CPW; i++) gload16(gp[i], lbase + lofs[i]);

  for (int k0 = 0; k0 < K; k0 += 32) {
    int p = (k0 >> 5) & 1;
    __syncthreads();  // drains buffer-p loads; prev compute done
    if (k0 + 32 < K) {
      int pofs = (p ^ 1) * (SB * 2);
#pragma unroll
      for (int i = 0; i < CPW; i++) gload16(gp[i] + k0 + 32, lbase + pofs + lofs[i]);
    }
    bf16x8 af[MI], bfr[NI];
#pragma unroll
    for (int i = 0; i < MI; i++)
      af[i] = *(const bf16x8*)&Ls[p][(wm + i * 16 + l16) * 32 + quad * 8];
#pragma unroll
    for (int j = 0; j < NI; j++)
      bfr[j] = *(const bf16x8*)&Ls[p][4096 + (wn + j * 16 + l16) * 32 + quad * 8];
#pragma unroll
    for (int mi = 0; mi < MI; mi++)
#pragma unroll
      for (int ni = 0; ni < NI; ni++)
        acc[mi][ni] = __builtin_amdgcn_mfma_f32_16x16x32_bf16(af[mi], bfr[ni], acc[mi][ni], 0, 0, 0);
  }

  // epilogue: lane l16 tile ni = column n0 + wn + l16*4 + ni (4 consecutive)
  size_t cbase = (size_t)bz * sC;
  int gnb = n0 + wn + l16 * 4;
  float cs4[4] = {1.f, 1.f, 1.f, 1.f};
  if (colscale) {
    float4 c4 = *(const float4*)&colscale[(size_t)bz * N + gnb];
    cs4[0] = 1.f / c4.x; cs4[1] = 1.f / c4.y; cs4[2] = 1.f / c4.z; cs4[3] = 1.f / c4.w;
  }
  float b4[4] = {0.f, 0.f, 0.f, 0.f};
  if (bias_mode == 2) {
    float4 t4 = *(const float4*)&bias[gnb];
    b4[0] = t4.x; b4[1] = t4.y; b4[2] = t4.z; b4[3] = t4.w;
  }
#pragma unroll
  for (int mi = 0; mi < MI; mi++) {
#pragma unroll
    for (int r = 0; r < 4; r++) {
      int m = m0 + wm + mi * 16 + quad * 4 + r;
      float rbias = (bias_mode == 1) ? bias[m] : 0.f;
      float v4[4];
      float rs = 0.f;
#pragma unroll
      for (int ni = 0; ni < NI; ni++) {
        float val = acc[mi][ni][r];
        if (colscale) val *= cs4[ni];
        val += (bias_mode == 2) ? b4[ni] : rbias;
        val *= scale;
        if (rowsum) { val = __expf(val); rs += val; }
        v4[ni] = val;
      }
      size_t idx = cbase + (size_t)m * ldc + gnb;
      if (outF) {
        float4 rv = *(const float4*)&resid[idx];
        float4 ov = make_float4(v4[0] + rv.x, v4[1] + rv.y, v4[2] + rv.z, v4[3] + rv.w);
        *(float4*)&outF[idx] = ov;
      } else {
        unsigned lo = (unsigned)f2bf(v4[0]) | ((unsigned)f2bf(v4[1]) << 16);
        unsigned hi = (unsigned)f2bf(v4[2]) | ((unsigned)f2bf(v4[3]) << 16);
        *(uint2*)&outB[idx] = make_uint2(lo, hi);
      }
      if (rowsum) {
        rs += __shfl_xor(rs, 1, 64);
        rs += __shfl_xor(rs, 2, 64);
        rs += __shfl_xor(rs, 4, 64);
        rs += __shfl_xor(rs, 8, 64);
        if (l16 == 0) atomicAdd(&rowsum[(size_t)bz * 4096 + m], rs);
      }
    }
  }
}

extern "C" void kernel_launch(void* const* d_in, const int* in_sizes, int n_in,
                              void* d_out, int out_size, void* d_ws, size_t ws_size,
                              hipStream_t stream) {
  const float* x     = (const float*)d_in[0];
  const float* gamma = (const float*)d_in[1];
  const float* beta  = (const float*)d_in[2];
  const float* wq    = (const float*)d_in[3];
  const float* bq    = (const float*)d_in[4];
  const float* wk    = (const float*)d_in[5];
  const float* bk    = (const float*)d_in[6];
  const float* wv    = (const float*)d_in[7];
  const float* bv    = (const float*)d_in[8];
  const float* wo    = (const float*)d_in[9];
  const float* bo    = (const float*)d_in[10];
  float* out = (float*)d_out;

  // workspace layout (bf16 elements)
  ushort_t* wb  = (ushort_t*)d_ws;     // [wq;wk] 1024x512, wv, wo
  ushort_t* wvb = wb + 524288;
  ushort_t* wob = wb + 786432;
  ushort_t* hnT = wb + 1048576;        // 2 x 4096 x 512
  ushort_t* qkT = hnT + 4194304;       // 2 x 4096 x 1024 (q cols 0-511, k cols 512-1023)
  ushort_t* vC  = qkT + 8388608;       // 2 x 512 x 4096
  ushort_t* OT  = vC + 4194304;        // 2 x 4096 x 512
  ushort_t* S   = OT + 4194304;        // 2 x 4096 x 4096 (holds P = exp(scale*S))
  float* fbuf   = (float*)(S + 33554432);
  float* stats  = fbuf;                // 128
  float* stats2 = fbuf + 128;          // 128
  float* qkbias = fbuf + 256;          // 1024
  float* l      = (float*)hnT;         // 2 x 4096 row sums (hnT dead after v-GEMM)

  const long long HS = 2097152;   // 4096*512 per batch
  const long long QS = 4194304;   // 4096*1024 per batch
  const long long SS = 16777216;  // 4096*4096 per batch
  const float scale = 0.044194173824159216f;  // 512^-0.5

  cvt_weights<<<dim3(1029), dim3(256), 0, stream>>>(wq, wk, wv, wo, bq, bk, wb, qkbias, stats2);
  gn_stats_partial<<<dim3(256), dim3(256), 0, stream>>>(x, stats2);
  gn_finalize<<<dim3(1), dim3(64), 0, stream>>>(stats2, stats);
  gn_apply<<<dim3(128, 16, 2), dim3(32, 8), 0, stream>>>(x, gamma, beta, stats, hnT);
  // qkT = hnT * [wq;wk]^T  (M=4096, N=1024, K=512), packed col bias
  gemm_abt<128><<<dim3(8, 32, 2), dim3(256), 0, stream>>>(
      hnT, HS, 512, wb, 0, 512, 512, 1024, 1024, qkT, QS, qkbias, 2, 1.f,
      nullptr, nullptr, nullptr, nullptr, 1);
  // vC = wv * hnT^T  (M=512, N=4096, K=512), row bias (natural order: B-sharing
  // blocks are already stride-64 apart -> same XCD)
  gemm_abt<64><<<dim3(64, 4, 2), dim3(256), 0, stream>>>(
      wvb, 0, 512, hnT, HS, 512, 512, 4096, 4096, vC, HS, bv, 1, 1.f,
      nullptr, nullptr, nullptr, nullptr, 0);
  // hnT dead; reuse as rowsum l
  zero_f32<<<dim3(32), dim3(256), 0, stream>>>(l);
  // P = exp(scale * q*k^T) with fused row sums (M=N=4096, K=512)
  gemm_abt<128><<<dim3(32, 32, 2), dim3(256), 0, stream>>>(
      qkT, QS, 1024, qkT + 512, QS, 1024, 512, 4096, 4096, S, SS, nullptr, 0, scale,
      nullptr, nullptr, l, nullptr, 1);
  // OT = P * vC^T (M=4096, N=512, K=4096), unnormalized; swizzle so the 8
  // same-P-row blocks share one XCD's L2
  gemm_abt<64><<<dim3(8, 32, 2), dim3(256), 0, stream>>>(
      S, SS, 4096, vC, HS, 4096, 4096, 512, 512, OT, HS, nullptr, 0, 1.f,
      nullptr, nullptr, nullptr, nullptr, 1);
  // y = wo * (OT/l)^T + bo + x (M=512, N=4096, K=512), fp32 out + residual
  gemm_abt<64><<<dim3(64, 4, 2), dim3(256), 0, stream>>>(
      wob, 0, 512, OT, HS, 512, 512, 4096, 4096, nullptr, HS, bo, 1, 1.f,
      out, x, nullptr, l, 0);
}